// Round 11
// baseline (4917.067 us; speedup 1.0000x reference)
//
#include <hip/hip_runtime.h>
#include <hip/hip_bf16.h>
#include <cstdint>

#define HIDDEN 1024
#define INPUT  256
#define BATCH  64
#define TSTEPS 512
#define NGCOL  4096      // 4*HIDDEN
#define KTOT   1280      // HIDDEN + INPUT
#define HBUFN  65536     // BATCH*HIDDEN u32 per parity buffer
#define STAGEN 65536     // u32 per parity per XCD staging
#define NXCD   8

typedef __attribute__((ext_vector_type(8))) short bf16x8;
typedef __attribute__((ext_vector_type(4))) float f32x4;
typedef unsigned long long u64;
typedef unsigned int u32;

__device__ inline short f2bs(float f) {
    union { __hip_bfloat16 h; short s; } u;
    u.h = __float2bfloat16(f);
    return u.s;
}
__device__ inline unsigned short f2bu(float f) {
    union { __hip_bfloat16 h; unsigned short s; } u;
    u.h = __float2bfloat16(f);
    return u.s;
}

// ---------------------------------------------------------------------------
// P1: build unified transposed bf16 weights Wt[4096 cols][1280 k]
__global__ __launch_bounds__(256) void build_wt(
    const float* __restrict__ Whh, const float* __restrict__ Wih,
    __hip_bfloat16* __restrict__ Wt)
{
    int t = blockIdx.x * 256 + threadIdx.x;   // 0 .. 4096*80-1
    int col = t & 4095;
    int k0  = (t >> 12) * 16;                 // 0..1264
    __hip_bfloat16 tmp[16];
    if (k0 < HIDDEN) {
        #pragma unroll
        for (int i = 0; i < 16; ++i)
            tmp[i] = __float2bfloat16(Whh[(size_t)(k0 + i) * NGCOL + col]);
    } else {
        #pragma unroll
        for (int i = 0; i < 16; ++i)
            tmp[i] = __float2bfloat16(Wih[(size_t)(k0 - HIDDEN + i) * NGCOL + col]);
    }
    #pragma unroll
    for (int i = 0; i < 16; ++i)
        Wt[(size_t)col * KTOT + k0 + i] = tmp[i];
}

// ---------------------------------------------------------------------------
// P2: bias = b_ih + b_hh ; zero h buffers, per-XCD staging, rank counters
__global__ __launch_bounds__(256) void init_state(
    const float* __restrict__ bih, const float* __restrict__ bhh,
    float* __restrict__ bias, u32* __restrict__ hbuf,
    u32* __restrict__ staging, u32* __restrict__ cnt)
{
    int i = blockIdx.x * 256 + threadIdx.x;   // 1,048,576 threads
    if (i < NGCOL) bias[i] = bih[i] + bhh[i];
    if (i < 2 * HBUFN) hbuf[i] = 0u;
    staging[i] = 0u;                          // 2*8*65536 = 1,048,576 u32
    if (i < 256) cnt[i] = 0u;
}

// ---------------------------------------------------------------------------
// Persistent LSTM with per-XCD relay broadcast.
//   produce:  sc1 store epoch-coded u32 ((t+1)<<16 | bf16) to global hbuf
//   relay:    each wave sc1-reads a 1KB slice of hbuf (spin on epochs),
//             plain-stores it into THIS XCD's staging -> local L2 fresh
//   consume:  volatile (sc0) sweep of staging slice, spin on epochs;
//             bounded retries then sc1-fallback (placement-safe, G16)
// 256 wgs: bg = wg>>6 (16 batch rows), cg = wg&63 (16 h-cols -> 64 gate cols).
__global__ __launch_bounds__(512, 2) void lstm_persist(
    const __hip_bfloat16* __restrict__ Wt,
    const float* __restrict__ x,
    u32* __restrict__ hbuf,              // [2][64][1024] epoch-coded
    u32* __restrict__ staging,           // [NXCD][2][64][1024]
    float* __restrict__ hf,
    const float* __restrict__ bias,
    u32* __restrict__ cnt)               // [8 xcd + 1 grand] padded x16
{
    __shared__ float pbuf[8][1025];
    __shared__ u32 pro[3];               // xcd, rank, n_x

    const int tid  = threadIdx.x;
    const int wg   = blockIdx.x;
    const int bg   = wg >> 6;         // 0..3
    const int cg   = wg & 63;         // 0..63
    const int wave = tid >> 6;
    const int lane = tid & 63;
    const int l15  = lane & 15;
    const int l4   = lane >> 4;
    const int b0   = bg * 16;
    const int n0   = cg * 16;

    // ---- one-time XCD rank discovery (placement-independent correctness)
    if (tid == 0) {
        u32 xcc;
        asm volatile("s_getreg_b32 %0, hwreg(HW_REG_XCC_ID)" : "=s"(xcc));
        xcc &= 7u;
        u32 rank = __hip_atomic_fetch_add(cnt + xcc * 16, 1u,
                                          __ATOMIC_RELAXED, __HIP_MEMORY_SCOPE_AGENT);
        __hip_atomic_fetch_add(cnt + 8 * 16, 1u,
                               __ATOMIC_RELAXED, __HIP_MEMORY_SCOPE_AGENT);
        while (__hip_atomic_load(cnt + 8 * 16, __ATOMIC_RELAXED,
                                 __HIP_MEMORY_SCOPE_AGENT) < 256u)
            __builtin_amdgcn_s_sleep(2);
        u32 nx = __hip_atomic_load(cnt + xcc * 16, __ATOMIC_RELAXED,
                                   __HIP_MEMORY_SCOPE_AGENT);
        pro[0] = xcc; pro[1] = rank; pro[2] = nx;
    }
    __syncthreads();
    const u32 myxcd = pro[0];
    const u32 nw    = pro[2] * 8u;            // waves on my XCD
    const u32 rw    = pro[1] * 8u + (u32)wave; // my wave's relay id

    // ---- weight slice (plain cached loads; L2-resident, off critical path)
    const __hip_bfloat16* wrow = Wt + (size_t)(n0 + l15) * KTOT;
    bf16x8 w[5][4];
    #pragma unroll
    for (int c5 = 0; c5 < 5; ++c5) {
        const int kk = (wave + c5 * 8) * 32 + l4 * 8;
        #pragma unroll
        for (int g = 0; g < 4; ++g)
            w[c5][g] = *(const bf16x8*)(wrow + (size_t)g * 1024 * KTOT + kk);
    }

    // ---- persistent per-thread state for reducer threads (tid<256)
    const int br = tid >> 4;
    const int hc = tid & 15;
    float creg = 0.f;
    float bi = 0.f, bfr = 0.f, bgg = 0.f, bo = 0.f;
    if (tid < 256) {
        bi  = bias[0 * 1024 + n0 + hc];
        bfr = bias[1 * 1024 + n0 + hc];
        bgg = bias[2 * 1024 + n0 + hc];
        bo  = bias[3 * 1024 + n0 + hc];
    }

    const int hoff = (b0 + l15) * HIDDEN + wave * 32 + l4 * 8;   // u32 units
    const float* xrow = x + ((size_t)(b0 + l15) * TSTEPS) * INPUT + wave * 32 + l4 * 8;

    for (int t = 0; t < TSTEPS; ++t) {
        const u32* hb = hbuf + (t & 1) * HBUFN;        // epoch t (global)
        u32*       ho = hbuf + ((t + 1) & 1) * HBUFN;  // epoch t+1 (global)
        u32*       sg = staging + ((size_t)myxcd * 2 + (t & 1)) * STAGEN;

        const u64 want  = ((u64)(u32)t << 16) | ((u64)(u32)t << 48);
        const u64 emask = 0xFFFF0000FFFF0000ull;

        // ---- issue x loads early (latency hides under relay)
        const float* xf = xrow + (size_t)t * INPUT;
        float4 pa = *(const float4*)(xf);
        float4 pb = *(const float4*)(xf + 4);

        // ---- relay: copy owned 1KB slices of fresh h into local staging
        for (u32 s = rw; s < 256u; s += nw) {
            const u32 off = (s >> 2) * 1024u + (s & 3u) * 256u + (u32)lane * 4u;
            const u64* sp = (const u64*)(hb + off);
            u64 d0, d1;
            for (;;) {
                d0 = __hip_atomic_load(sp,     __ATOMIC_RELAXED, __HIP_MEMORY_SCOPE_AGENT);
                d1 = __hip_atomic_load(sp + 1, __ATOMIC_RELAXED, __HIP_MEMORY_SCOPE_AGENT);
                if (__all((((d0 ^ want) | (d1 ^ want)) & emask) == 0ull)) break;
                __builtin_amdgcn_s_sleep(1);
            }
            u64* dp = (u64*)(sg + off);
            dp[0] = d0; dp[1] = d1;          // plain store -> local L2 fresh
        }

        // ---- x fragment + x-part MFMAs (independent of h)
        bf16x8 afx;
        afx[0] = f2bs(pa.x); afx[1] = f2bs(pa.y); afx[2] = f2bs(pa.z); afx[3] = f2bs(pa.w);
        afx[4] = f2bs(pb.x); afx[5] = f2bs(pb.y); afx[6] = f2bs(pb.z); afx[7] = f2bs(pb.w);
        f32x4 a0 = {0.f, 0.f, 0.f, 0.f};
        f32x4 a1 = a0, a2 = a0, a3 = a0;
        a0 = __builtin_amdgcn_mfma_f32_16x16x32_bf16(afx, w[4][0], a0, 0, 0, 0);
        a1 = __builtin_amdgcn_mfma_f32_16x16x32_bf16(afx, w[4][1], a1, 0, 0, 0);
        a2 = __builtin_amdgcn_mfma_f32_16x16x32_bf16(afx, w[4][2], a2, 0, 0, 0);
        a3 = __builtin_amdgcn_mfma_f32_16x16x32_bf16(afx, w[4][3], a3, 0, 0, 0);

        // ---- consume: sweep local staging (sc0), bounded -> sc1 fallback
        u64 hq[4][4];
        {
            int tries = 0; bool ok = false;
            while (!ok) {
                u64 bad = 0;
                #pragma unroll
                for (int c5 = 0; c5 < 4; ++c5) {
                    volatile const u64* vp = (volatile const u64*)(sg + hoff + c5 * 256);
                    #pragma unroll
                    for (int q = 0; q < 4; ++q) {
                        hq[c5][q] = vp[q];
                        bad |= (hq[c5][q] ^ want) & emask;
                    }
                }
                ok = __all(bad == 0);
                if (!ok && ++tries > 2048) break;
            }
            if (!ok) {   // placement-anomaly fallback: direct sc1 global sweep
                for (;;) {
                    u64 bad = 0;
                    #pragma unroll
                    for (int c5 = 0; c5 < 4; ++c5) {
                        const u64* hp = (const u64*)(hb + hoff + c5 * 256);
                        #pragma unroll
                        for (int q = 0; q < 4; ++q) {
                            hq[c5][q] = __hip_atomic_load(hp + q, __ATOMIC_RELAXED,
                                                          __HIP_MEMORY_SCOPE_AGENT);
                            bad |= (hq[c5][q] ^ want) & emask;
                        }
                    }
                    if (__all(bad == 0)) break;
                    __builtin_amdgcn_s_sleep(1);
                }
            }
        }
        // ---- repack: u64 (2 epoch-coded u32) -> packed bf16 pair
        bf16x8 afh[4];
        #pragma unroll
        for (int c5 = 0; c5 < 4; ++c5) {
            union { u32 p[4]; bf16x8 v; } u;
            #pragma unroll
            for (int q = 0; q < 4; ++q) {
                const u64 d = hq[c5][q];
                u.p[q] = (u32)(d & 0xFFFFu) | ((u32)(d >> 32) << 16);
            }
            afh[c5] = u.v;
        }

        #pragma unroll
        for (int c5 = 0; c5 < 4; ++c5) {
            a0 = __builtin_amdgcn_mfma_f32_16x16x32_bf16(afh[c5], w[c5][0], a0, 0, 0, 0);
            a1 = __builtin_amdgcn_mfma_f32_16x16x32_bf16(afh[c5], w[c5][1], a1, 0, 0, 0);
            a2 = __builtin_amdgcn_mfma_f32_16x16x32_bf16(afh[c5], w[c5][2], a2, 0, 0, 0);
            a3 = __builtin_amdgcn_mfma_f32_16x16x32_bf16(afh[c5], w[c5][3], a3, 0, 0, 0);
        }

        // D layout: row (batch) = l4*4 + r, col (h-col) = l15
        float* pw = &pbuf[wave][0];
        #pragma unroll
        for (int r = 0; r < 4; ++r) {
            const int row = l4 * 4 + r;
            pw[(0 * 16 + row) * 16 + l15] = a0[r];
            pw[(1 * 16 + row) * 16 + l15] = a1[r];
            pw[(2 * 16 + row) * 16 + l15] = a2[r];
            pw[(3 * 16 + row) * 16 + l15] = a3[r];
        }
        __syncthreads();

        if (tid < 256) {
            float gi = bi, gf = bfr, gg = bgg, go = bo;
            #pragma unroll
            for (int w8 = 0; w8 < 8; ++w8) {
                const float* p = &pbuf[w8][0];
                gi += p[(0 * 16 + br) * 16 + hc];
                gf += p[(1 * 16 + br) * 16 + hc];
                gg += p[(2 * 16 + br) * 16 + hc];
                go += p[(3 * 16 + br) * 16 + hc];
            }
            const float i_ = 1.f / (1.f + __expf(-gi));
            const float f_ = 1.f / (1.f + __expf(-gf));
            const float g_ = tanhf(gg);
            const float o_ = 1.f / (1.f + __expf(-go));
            creg = f_ * creg + i_ * g_;
            const float h = o_ * tanhf(creg);
            if (t == TSTEPS - 1) {
                hf[(b0 + br) * HIDDEN + n0 + hc] = h;
            } else {
                const u32 val = ((u32)(t + 1) << 16) | (u32)f2bu(h);
                __hip_atomic_store(ho + (b0 + br) * HIDDEN + n0 + hc, val,
                                   __ATOMIC_RELAXED, __HIP_MEMORY_SCOPE_AGENT);
            }
        }
        if (t == TSTEPS - 1) break;
        __syncthreads();   // pbuf safe for next step
    }
}

// ---------------------------------------------------------------------------
// Epilogue: out[64][256] = h_last(fp32) @ W_out + b_out
__global__ __launch_bounds__(256) void out_proj(
    const float* __restrict__ hf, const float* __restrict__ Wout,
    const float* __restrict__ bout, float* __restrict__ out)
{
    const int b  = blockIdx.x;    // 64
    const int oc = threadIdx.x;   // 256
    const float* hb = hf + (size_t)b * HIDDEN;
    float a0 = 0.f, a1 = 0.f, a2 = 0.f, a3 = 0.f;
    for (int k = 0; k < HIDDEN; k += 4) {
        a0 += hb[k + 0] * Wout[(size_t)(k + 0) * 256 + oc];
        a1 += hb[k + 1] * Wout[(size_t)(k + 1) * 256 + oc];
        a2 += hb[k + 2] * Wout[(size_t)(k + 2) * 256 + oc];
        a3 += hb[k + 3] * Wout[(size_t)(k + 3) * 256 + oc];
    }
    out[b * 256 + oc] = (a0 + a1) + (a2 + a3) + bout[oc];
}

// ---------------------------------------------------------------------------
extern "C" void kernel_launch(void* const* d_in, const int* in_sizes, int n_in,
                              void* d_out, int out_size, void* d_ws, size_t ws_size,
                              hipStream_t stream)
{
    const float* x    = (const float*)d_in[0];
    const float* Wih  = (const float*)d_in[1];
    const float* Whh  = (const float*)d_in[2];
    const float* bih  = (const float*)d_in[3];
    const float* bhh  = (const float*)d_in[4];
    const float* Wout = (const float*)d_in[5];
    const float* bout = (const float*)d_in[6];
    float* out = (float*)d_out;

    char* ws = (char*)d_ws;
    size_t off = 0;
    auto alloc = [&](size_t bytes) -> void* {
        void* p = ws + off;
        off = (off + bytes + 255) & ~(size_t)255;
        return p;
    };
    __hip_bfloat16* Wt = (__hip_bfloat16*)alloc((size_t)NGCOL * KTOT * 2);     // 10 MB
    u32*   hbuf    = (u32*)alloc((size_t)2 * HBUFN * 4);                       // 512 KB
    u32*   staging = (u32*)alloc((size_t)NXCD * 2 * STAGEN * 4);               // 4 MB
    float* bias    = (float*)alloc((size_t)NGCOL * 4);
    float* hf      = (float*)alloc((size_t)BATCH * HIDDEN * 4);
    u32*   cnt     = (u32*)alloc((size_t)256 * 4);                             // 1 KB

    build_wt<<<1280, 256, 0, stream>>>(Whh, Wih, Wt);
    init_state<<<4096, 256, 0, stream>>>(bih, bhh, bias, hbuf, staging, cnt);
    lstm_persist<<<256, 512, 0, stream>>>(Wt, x, hbuf, staging, hf, bias, cnt);
    out_proj<<<64, 256, 0, stream>>>(hf, Wout, bout, out);
}

// Round 12
// 2973.309 us; speedup vs baseline: 1.6537x; 1.6537x over previous
//
#include <hip/hip_runtime.h>
#include <hip/hip_bf16.h>
#include <cstdint>

#define HIDDEN 1024
#define INPUT  256
#define BATCH  64
#define TSTEPS 512
#define NGCOL  4096      // 4*HIDDEN
#define KTOT   1280      // HIDDEN + INPUT
#define HBUFN  65536     // BATCH*HIDDEN u32 per parity buffer

typedef __attribute__((ext_vector_type(8))) short bf16x8;
typedef __attribute__((ext_vector_type(4))) float f32x4;
typedef unsigned long long u64;
typedef unsigned int u32;

__device__ inline short f2bs(float f) {
    union { __hip_bfloat16 h; short s; } u;
    u.h = __float2bfloat16(f);
    return u.s;
}
__device__ inline unsigned short f2bu(float f) {
    union { __hip_bfloat16 h; unsigned short s; } u;
    u.h = __float2bfloat16(f);
    return u.s;
}

// ---------------------------------------------------------------------------
// P1: build unified transposed bf16 weights Wt[4096 cols][1280 k]
__global__ __launch_bounds__(256) void build_wt(
    const float* __restrict__ Whh, const float* __restrict__ Wih,
    __hip_bfloat16* __restrict__ Wt)
{
    int t = blockIdx.x * 256 + threadIdx.x;   // 0 .. 4096*80-1
    int col = t & 4095;
    int k0  = (t >> 12) * 16;                 // 0..1264
    __hip_bfloat16 tmp[16];
    if (k0 < HIDDEN) {
        #pragma unroll
        for (int i = 0; i < 16; ++i)
            tmp[i] = __float2bfloat16(Whh[(size_t)(k0 + i) * NGCOL + col]);
    } else {
        #pragma unroll
        for (int i = 0; i < 16; ++i)
            tmp[i] = __float2bfloat16(Wih[(size_t)(k0 - HIDDEN + i) * NGCOL + col]);
    }
    #pragma unroll
    for (int i = 0; i < 16; ++i)
        Wt[(size_t)col * KTOT + k0 + i] = tmp[i];
}

// ---------------------------------------------------------------------------
// P2: bias = b_ih + b_hh ; zero both epoch-coded h buffers (epoch 0, h=0)
__global__ __launch_bounds__(256) void init_state(
    const float* __restrict__ bih, const float* __restrict__ bhh,
    float* __restrict__ bias, u32* __restrict__ hbuf)
{
    int i = blockIdx.x * 256 + threadIdx.x;   // 131072 threads
    if (i < NGCOL) bias[i] = bih[i] + bhh[i];
    hbuf[i] = 0u;                              // both parity buffers
}

// ---------------------------------------------------------------------------
// Persistent LSTM — minimal-hop in-band protocol (all sc1 relaxed-agent):
//   data:     u32 = (epoch<<16) | bf16(h), epoch = t+1. Producers store and
//             move on: NO drain, NO flag, NO fence.
//   detect:   consumer lanes poll 4B DATA SENTINELS (one element per
//             producer reducer-wave; 32 sentinels x2 redundancy across 64
//             lanes) -- tiny poll traffic, 1-hop visibility.
//   sweep:    burst 16 parallel u64 loads, verify embedded epochs; rare
//             PARALLEL re-sweep (r6-style) as the true gate.
// XCD-swizzled logical tile mapping: cg=(i&7)*8+((i>>3)&7), bg=i>>6 --
// per-XCD weight working set 8 slices = 1.28 MB (L2-resident).
__global__ __launch_bounds__(512, 2) void lstm_persist(
    const __hip_bfloat16* __restrict__ Wt,
    const float* __restrict__ x,
    u32* __restrict__ hbuf,              // [2][64][1024] epoch-coded
    float* __restrict__ hf,
    const float* __restrict__ bias)
{
    __shared__ float pbuf[8][1025];

    const int tid  = threadIdx.x;
    const int i    = blockIdx.x;
    const int cg   = (i & 7) * 8 + ((i >> 3) & 7);  // 0..63 (XCD-clustered)
    const int bg   = i >> 6;                        // 0..3
    const int wave = tid >> 6;
    const int lane = tid & 63;
    const int l15  = lane & 15;
    const int l4   = lane >> 4;
    const int b0   = bg * 16;
    const int n0   = cg * 16;

    // ---- weight slice (cached loads; L2-resident via XCD clustering)
    const __hip_bfloat16* wrow = Wt + (size_t)(n0 + l15) * KTOT;
    bf16x8 w[5][4];
    #pragma unroll
    for (int c5 = 0; c5 < 5; ++c5) {
        const int kk = (wave + c5 * 8) * 32 + l4 * 8;
        #pragma unroll
        for (int g = 0; g < 4; ++g)
            w[c5][g] = *(const bf16x8*)(wrow + (size_t)g * 1024 * KTOT + kk);
    }

    // ---- persistent per-thread state for reducer threads (tid<256)
    const int br = tid >> 4;          // batch row within group
    const int hc = tid & 15;          // h-col within group
    float creg = 0.f;
    float bi = 0.f, bfr = 0.f, bgg = 0.f, bo = 0.f;
    if (tid < 256) {
        bi  = bias[0 * 1024 + n0 + hc];
        bfr = bias[1 * 1024 + n0 + hc];
        bgg = bias[2 * 1024 + n0 + hc];
        bo  = bias[3 * 1024 + n0 + hc];
    }

    const int hoff = (b0 + l15) * HIDDEN + wave * 32 + l4 * 8;   // u32 units
    const float* xrow = x + ((size_t)(b0 + l15) * TSTEPS) * INPUT + wave * 32 + l4 * 8;

    // sentinel map: this wave's 8 producers (union over 8 waves = all 64 cgs)
    const int jj  = lane & 7;
    const int rr  = (lane >> 3) & 3;                 // producer reducer-wave
    const int pcg = 2 * wave + (jj & 1) + 16 * ((jj >> 1) & 3);
    const int sentoff = (b0 + 4 * rr + 3) * HIDDEN + pcg * 16 + ((lane >= 32) ? 7 : 15);

    for (int t = 0; t < TSTEPS; ++t) {
        const u32* hb = hbuf + (t & 1) * HBUFN;        // holds epoch t
        u32*       ho = hbuf + ((t + 1) & 1) * HBUFN;  // receives epoch t+1

        // ---- x fragment + x-part MFMAs first (independent of h)
        bf16x8 afx;
        {
            const float* xf = xrow + (size_t)t * INPUT;
            float4 pa = *(const float4*)(xf);
            float4 pb = *(const float4*)(xf + 4);
            afx[0] = f2bs(pa.x); afx[1] = f2bs(pa.y); afx[2] = f2bs(pa.z); afx[3] = f2bs(pa.w);
            afx[4] = f2bs(pb.x); afx[5] = f2bs(pb.y); afx[6] = f2bs(pb.z); afx[7] = f2bs(pb.w);
        }
        f32x4 a0 = {0.f, 0.f, 0.f, 0.f};
        f32x4 a1 = a0, a2 = a0, a3 = a0;
        a0 = __builtin_amdgcn_mfma_f32_16x16x32_bf16(afx, w[4][0], a0, 0, 0, 0);
        a1 = __builtin_amdgcn_mfma_f32_16x16x32_bf16(afx, w[4][1], a1, 0, 0, 0);
        a2 = __builtin_amdgcn_mfma_f32_16x16x32_bf16(afx, w[4][2], a2, 0, 0, 0);
        a3 = __builtin_amdgcn_mfma_f32_16x16x32_bf16(afx, w[4][3], a3, 0, 0, 0);

        // ---- sentinel detect: 4B data-element polls (1-hop visibility)
        {
            const u32 wantu = (u32)t << 16;
            for (;;) {
                u32 v = __hip_atomic_load(hb + sentoff, __ATOMIC_RELAXED,
                                          __HIP_MEMORY_SCOPE_AGENT);
                if (__all(((v ^ wantu) & 0xFFFF0000u) == 0)) break;
                __builtin_amdgcn_s_sleep(1);
            }
        }

        // ---- burst sweep (16 parallel u64) + verify; rare parallel re-sweep
        const u64 want  = ((u64)(u32)t << 16) | ((u64)(u32)t << 48);
        const u64 emask = 0xFFFF0000FFFF0000ull;
        u64 hq[4][4];
        {
            u64 bad = 0;
            #pragma unroll
            for (int c5 = 0; c5 < 4; ++c5) {
                const u64* hp = (const u64*)(hb + hoff + c5 * 256);
                #pragma unroll
                for (int q = 0; q < 4; ++q) {
                    hq[c5][q] = __hip_atomic_load(hp + q, __ATOMIC_RELAXED,
                                                  __HIP_MEMORY_SCOPE_AGENT);
                    bad |= (hq[c5][q] ^ want) & emask;
                }
            }
            while (!__all(bad == 0)) {          // stragglers: full parallel re-sweep
                __builtin_amdgcn_s_sleep(1);
                bad = 0;
                #pragma unroll
                for (int c5 = 0; c5 < 4; ++c5) {
                    const u64* hp = (const u64*)(hb + hoff + c5 * 256);
                    #pragma unroll
                    for (int q = 0; q < 4; ++q) {
                        hq[c5][q] = __hip_atomic_load(hp + q, __ATOMIC_RELAXED,
                                                      __HIP_MEMORY_SCOPE_AGENT);
                        bad |= (hq[c5][q] ^ want) & emask;
                    }
                }
            }
        }
        // ---- repack: u64 (2 epoch-coded u32) -> packed bf16 pair
        bf16x8 afh[4];
        #pragma unroll
        for (int c5 = 0; c5 < 4; ++c5) {
            union { u32 p[4]; bf16x8 v; } u;
            #pragma unroll
            for (int q = 0; q < 4; ++q) {
                const u64 d = hq[c5][q];
                u.p[q] = (u32)(d & 0xFFFFu) | ((u32)(d >> 32) << 16);
            }
            afh[c5] = u.v;
        }

        #pragma unroll
        for (int c5 = 0; c5 < 4; ++c5) {
            a0 = __builtin_amdgcn_mfma_f32_16x16x32_bf16(afh[c5], w[c5][0], a0, 0, 0, 0);
            a1 = __builtin_amdgcn_mfma_f32_16x16x32_bf16(afh[c5], w[c5][1], a1, 0, 0, 0);
            a2 = __builtin_amdgcn_mfma_f32_16x16x32_bf16(afh[c5], w[c5][2], a2, 0, 0, 0);
            a3 = __builtin_amdgcn_mfma_f32_16x16x32_bf16(afh[c5], w[c5][3], a3, 0, 0, 0);
        }

        // D layout: row (batch) = l4*4 + r, col (h-col) = l15
        float* pw = &pbuf[wave][0];
        #pragma unroll
        for (int r = 0; r < 4; ++r) {
            const int row = l4 * 4 + r;
            pw[(0 * 16 + row) * 16 + l15] = a0[r];
            pw[(1 * 16 + row) * 16 + l15] = a1[r];
            pw[(2 * 16 + row) * 16 + l15] = a2[r];
            pw[(3 * 16 + row) * 16 + l15] = a3[r];
        }
        __syncthreads();

        if (tid < 256) {
            float gi = bi, gf = bfr, gg = bgg, go = bo;
            #pragma unroll
            for (int w8 = 0; w8 < 8; ++w8) {
                const float* p = &pbuf[w8][0];
                gi += p[(0 * 16 + br) * 16 + hc];
                gf += p[(1 * 16 + br) * 16 + hc];
                gg += p[(2 * 16 + br) * 16 + hc];
                go += p[(3 * 16 + br) * 16 + hc];
            }
            const float i_ = 1.f / (1.f + __expf(-gi));
            const float f_ = 1.f / (1.f + __expf(-gf));
            const float g_ = tanhf(gg);
            const float o_ = 1.f / (1.f + __expf(-go));
            creg = f_ * creg + i_ * g_;
            const float h = o_ * tanhf(creg);
            if (t == TSTEPS - 1) {
                hf[(b0 + br) * HIDDEN + n0 + hc] = h;
            } else {
                // in-band store: epoch t+1 in high half; no drain, no flag
                const u32 val = ((u32)(t + 1) << 16) | (u32)f2bu(h);
                __hip_atomic_store(ho + (b0 + br) * HIDDEN + n0 + hc, val,
                                   __ATOMIC_RELAXED, __HIP_MEMORY_SCOPE_AGENT);
            }
        }
        if (t == TSTEPS - 1) break;
        __syncthreads();   // pbuf WAR for next step
    }
}

// ---------------------------------------------------------------------------
// Epilogue: out[64][256] = h_last(fp32) @ W_out + b_out
__global__ __launch_bounds__(256) void out_proj(
    const float* __restrict__ hf, const float* __restrict__ Wout,
    const float* __restrict__ bout, float* __restrict__ out)
{
    const int b  = blockIdx.x;    // 64
    const int oc = threadIdx.x;   // 256
    const float* hb = hf + (size_t)b * HIDDEN;
    float a0 = 0.f, a1 = 0.f, a2 = 0.f, a3 = 0.f;
    for (int k = 0; k < HIDDEN; k += 4) {
        a0 += hb[k + 0] * Wout[(size_t)(k + 0) * 256 + oc];
        a1 += hb[k + 1] * Wout[(size_t)(k + 1) * 256 + oc];
        a2 += hb[k + 2] * Wout[(size_t)(k + 2) * 256 + oc];
        a3 += hb[k + 3] * Wout[(size_t)(k + 3) * 256 + oc];
    }
    out[b * 256 + oc] = (a0 + a1) + (a2 + a3) + bout[oc];
}

// ---------------------------------------------------------------------------
extern "C" void kernel_launch(void* const* d_in, const int* in_sizes, int n_in,
                              void* d_out, int out_size, void* d_ws, size_t ws_size,
                              hipStream_t stream)
{
    const float* x    = (const float*)d_in[0];
    const float* Wih  = (const float*)d_in[1];
    const float* Whh  = (const float*)d_in[2];
    const float* bih  = (const float*)d_in[3];
    const float* bhh  = (const float*)d_in[4];
    const float* Wout = (const float*)d_in[5];
    const float* bout = (const float*)d_in[6];
    float* out = (float*)d_out;

    char* ws = (char*)d_ws;
    size_t off = 0;
    auto alloc = [&](size_t bytes) -> void* {
        void* p = ws + off;
        off = (off + bytes + 255) & ~(size_t)255;
        return p;
    };
    __hip_bfloat16* Wt = (__hip_bfloat16*)alloc((size_t)NGCOL * KTOT * 2); // 10 MB
    u32*   hbuf = (u32*)alloc((size_t)2 * HBUFN * 4);                      // 512 KB
    float* bias = (float*)alloc((size_t)NGCOL * 4);
    float* hf   = (float*)alloc((size_t)BATCH * HIDDEN * 4);

    build_wt<<<1280, 256, 0, stream>>>(Whh, Wih, Wt);
    init_state<<<512, 256, 0, stream>>>(bih, bhh, bias, hbuf);
    lstm_persist<<<256, 512, 0, stream>>>(Wt, x, hbuf, hf, bias);
    out_proj<<<64, 256, 0, stream>>>(hf, Wout, bout, out);
}